// Round 15
// baseline (126.630 us; speedup 1.0000x reference)
//
#include <hip/hip_runtime.h>
#include <hip/hip_bf16.h>

typedef __hip_bfloat16 bf16;
using short8 = __attribute__((ext_vector_type(8))) short;
using f32x4  = __attribute__((ext_vector_type(4))) float;

#define DEV static __device__ __forceinline__

DEV unsigned short f2bu(float f) {
  union { bf16 h; unsigned short u; } v; v.h = __float2bfloat16(f); return v.u;
}
DEV short f2bs(float f) {
  union { bf16 h; short s; } v; v.h = __float2bfloat16(f); return v.s;
}
DEV float bu2f(unsigned short u) {
  union { unsigned x; float f; } v; v.x = ((unsigned)u) << 16; return v.f;
}
DEV float lo2f(unsigned u) { union { unsigned x; float f; } v; v.x = u << 16; return v.f; }
DEV float hi2f(unsigned u) { union { unsigned x; float f; } v; v.x = u & 0xFFFF0000u; return v.f; }
DEV unsigned pk2(float a, float b) { return (unsigned)f2bu(a) | ((unsigned)f2bu(b) << 16); }

// ---- problem constants ----
#define N_ATOMS 2500
#define N_EDGES 40000

constexpr int cK[4]    = {128, 96, 64, 32};
constexpr int cPL[4]   = {0, 2, 2, 4};
constexpr int cLO[4]   = {96, 64, 32, 0};
constexpr int cAOF[4]  = {0, 1, 10, 19};
// ws float-offsets
constexpr int RAD2_OFF = 53248;                        // [pos][352 ushorts]
constexpr int S2_OFF   = RAD2_OFF + N_EDGES * 176;     // [pos][168 ushorts]
constexpr int UNC3_OFF = S2_OFF + N_EDGES * 84;        // [a][768 dwords]
constexpr int CCG_OFF  = UNC3_OFF + N_ATOMS * 768;     // [a][960 bf16]
constexpr int CSR_OFF   = CCG_OFF + N_ATOMS * 480;
constexpr int CNT_OFF   = CSR_OFF;
constexpr int START_OFF = CSR_OFF + 2500;
constexpr int FILL_OFF  = CSR_OFF + 5008;
constexpr int INV_OFF   = CSR_OFF + 47512;             // [e] -> pos
constexpr int NLIST_OFF = CSR_OFF + 87512;             // [pos] -> neighbor atom

constexpr int cCB[4]  = {0, 128, 416, 736};
constexpr int cOUT[4] = {0, 320000, 1040000, 1840000};

// couple/concat combo tables (constexpr for compile-time folding)
constexpr int ccl[30] = {0,0,0,0, 1,1,1,1,1,1,1,1,1, 2,2,2,2,2,2,2,2,2,2, 3,3,3,3,3,3,3};
constexpr int ccm[30] = {0,0,0,0, 0,0,0,1,1,1,2,2,2, 0,0,1,1,2,2,3,3,4,4, 0,1,2,3,4,5,6};
constexpr int ccs[30] = {0,1,2,3, 0,1,2,0,1,2,0,1,2, 0,1,0,1,0,1,0,1,0,1, 0,0,0,0,0,0,0};

// ---------------- k_count ----------------
__global__ __launch_bounds__(256) void k_count(const int* __restrict__ centers, int* __restrict__ cnt) {
  int e = blockIdx.x * 256 + threadIdx.x;
  if (e < N_EDGES) atomicAdd(&cnt[centers[e]], 1);
}

// ---------------- k_scan ----------------
__global__ __launch_bounds__(256) void k_scan(const int* __restrict__ cnt,
                                              int* __restrict__ start, int* __restrict__ fill) {
  __shared__ int part[256];
  int t = threadIdx.x;
  int loc[10];
  int s = 0;
  int base = t * 10;
#pragma unroll
  for (int i = 0; i < 10; ++i) {
    int c = (base + i < N_ATOMS) ? cnt[base + i] : 0;
    loc[i] = s; s += c;
  }
  part[t] = s;
  __syncthreads();
  for (int off = 1; off < 256; off <<= 1) {
    int v = part[t];
    if (t >= off) v += part[t - off];
    __syncthreads();
    part[t] = v;
    __syncthreads();
  }
  int excl = (t == 0) ? 0 : part[t - 1];
#pragma unroll
  for (int i = 0; i < 10; ++i) {
    if (base + i < N_ATOMS) {
      start[base + i] = excl + loc[i];
      fill[base + i]  = excl + loc[i];
    }
  }
  if (t == 255) start[N_ATOMS] = part[255];
}

// ---------------- k_fill ----------------
__global__ __launch_bounds__(256) void k_fill(const int* __restrict__ centers,
                                              const int* __restrict__ neighbors,
                                              int* __restrict__ fill,
                                              int* __restrict__ inv, int* __restrict__ nlist) {
  int e = blockIdx.x * 256 + threadIdx.x;
  if (e >= N_EDGES) return;
  int pos = atomicAdd(&fill[centers[e]], 1);
  inv[e] = pos;
  nlist[pos] = neighbors[e];
}

// ---------------- k_mid pieces ----------------
// UL layout: [0]=U0, [1..81]=U2, [82..706]=U4
DEV void sph_body(int e, int q,
                  const float* __restrict__ s0p, const float* __restrict__ s1p,
                  const float* __restrict__ s2p, const float* __restrict__ s3p,
                  const float* __restrict__ UL, const int* __restrict__ inv,
                  unsigned short* __restrict__ S2v) {
  float sp0 = s0p[e];
  float sp1[3], sp2[5], sp3[7];
#pragma unroll
  for (int m = 0; m < 3; ++m) sp1[m] = s1p[(long)e * 3 + m];
#pragma unroll
  for (int m = 0; m < 5; ++m) sp2[m] = s2p[(long)e * 5 + m];
#pragma unroll
  for (int m = 0; m < 7; ++m) sp3[m] = s3p[(long)e * 7 + m];
  unsigned short* out = S2v + (size_t)inv[e] * 168;
  if (q < 9) {
    const float* r = UL + 1 + q * 9;
    float s0 = r[0] * sp0;
    float s1 = r[1] * sp1[0] + r[2] * sp1[1] + r[3] * sp1[2];
    float s2 = r[4] * sp2[0] + r[5] * sp2[1] + r[6] * sp2[2] + r[7] * sp2[3] + r[8] * sp2[4];
    *reinterpret_cast<unsigned*>(out + 2 + 2 * q) = pk2(s0, s1);
    *reinterpret_cast<unsigned*>(out + 24 + 4 * q) = pk2(s0, s1);
    out[24 + 4 * q + 2] = f2bu(s2);
    out[24 + 4 * q + 3] = 0;
  }
  if (q < 25) {
    const float* r = UL + 82 + q * 25;
    float w0 = r[0] * sp0;
    float w1 = r[1] * sp1[0] + r[2] * sp1[1] + r[3] * sp1[2];
    float w2 = r[4] * sp2[0] + r[5] * sp2[1] + r[6] * sp2[2] + r[7] * sp2[3] + r[8] * sp2[4];
    float w3 = 0.f;
#pragma unroll
    for (int m = 0; m < 7; ++m) w3 += r[9 + m] * sp3[m];
    *reinterpret_cast<unsigned*>(out + 64 + 4 * q)     = pk2(w0, w1);
    *reinterpret_cast<unsigned*>(out + 64 + 4 * q + 2) = pk2(w2, w3);
  }
  if (q == 31) out[0] = f2bu(UL[0] * sp0);
}

template <int l>
DEV void radial_body(const float* __restrict__ rb, const float* __restrict__ Wr1f,
                     const float* __restrict__ w2, const int* __restrict__ inv,
                     unsigned short* __restrict__ rad2,
                     int e0, int tid, unsigned short (*H)[72]) {
  constexpr int NM = (l == 0) ? 8 : (l == 1) ? 6 : (l == 2) ? 4 : 2;
  constexpr int K  = cK[l];
  {
    int e  = e0 + (tid & 63);
    int j0 = (tid >> 6) * 16;
    float rbv[NM];
#pragma unroll
    for (int n = 0; n < NM; ++n) rbv[n] = rb[(long)e * NM + n];
    float h[16];
#pragma unroll
    for (int j = 0; j < 16; ++j) h[j] = 0.f;
#pragma unroll
    for (int n = 0; n < NM; ++n) {
      float rv = rbv[n];
      const float4* wp = reinterpret_cast<const float4*>(Wr1f + n * 64 + j0);
#pragma unroll
      for (int qq = 0; qq < 4; ++qq) {
        float4 w = wp[qq];
        h[4 * qq + 0] += rv * w.x;
        h[4 * qq + 1] += rv * w.y;
        h[4 * qq + 2] += rv * w.z;
        h[4 * qq + 3] += rv * w.w;
      }
    }
    unsigned short* hrow = H[tid & 63];
#pragma unroll
    for (int j = 0; j < 16; j += 2) {
      float a0 = h[j], a1 = h[j + 1];
      a0 = a0 * (1.0f / (1.0f + __expf(-a0)));
      a1 = a1 * (1.0f / (1.0f + __expf(-a1)));
      *reinterpret_cast<unsigned*>(&hrow[j0 + j]) = pk2(a0, a1);
    }
  }
  __syncthreads();
  int wv = tid >> 6, lane = tid & 63;
  constexpr int NET = (l <= 1) ? 4 : (l == 2 ? 2 : 1);
  int c0, et0;
  bool active = true;
  if constexpr (l == 0)      { c0 = wv * 32;       et0 = 0; }
  else if constexpr (l == 1) { c0 = wv * 32;       et0 = 0; active = (wv < 3); }
  else if constexpr (l == 2) { c0 = (wv & 1) * 32; et0 = (wv >> 1) * 2; }
  else                       { c0 = 0;             et0 = wv; }
  if (!active) return;
  int ln15 = lane & 15, lhi = lane >> 4;
  short8 Bf[2][2];
#pragma unroll
  for (int ct = 0; ct < 2; ++ct)
#pragma unroll
    for (int ks = 0; ks < 2; ++ks) {
      int col = c0 + ct * 16 + ln15;
      int kb  = ks * 32 + lhi * 8;
#pragma unroll
      for (int i = 0; i < 8; ++i)
        Bf[ct][ks][i] = f2bs(w2[(long)(kb + i) * K + col]);
    }
  int rowp[NET][4];
#pragma unroll
  for (int et = 0; et < NET; ++et)
#pragma unroll
    for (int r = 0; r < 4; ++r)
      rowp[et][r] = inv[e0 + (et0 + et) * 16 + lhi * 4 + r];
  f32x4 acc[NET][2];
#pragma unroll
  for (int et = 0; et < NET; ++et)
#pragma unroll
    for (int ct = 0; ct < 2; ++ct) acc[et][ct] = (f32x4){0.f, 0.f, 0.f, 0.f};
#pragma unroll
  for (int et = 0; et < NET; ++et) {
#pragma unroll
    for (int ks = 0; ks < 2; ++ks) {
      short8 Af = *reinterpret_cast<const short8*>(&H[(et0 + et) * 16 + ln15][ks * 32 + lhi * 8]);
      acc[et][0] = __builtin_amdgcn_mfma_f32_16x16x32_bf16(Af, Bf[0][ks], acc[et][0], 0, 0, 0);
      acc[et][1] = __builtin_amdgcn_mfma_f32_16x16x32_bf16(Af, Bf[1][ks], acc[et][1], 0, 0, 0);
    }
  }
#pragma unroll
  for (int ct = 0; ct < 2; ++ct) {
    int c = c0 + ct * 16 + ln15;
    int lsec = 3 - (c >> 5);
    int kk = c & 31;
    int sec  = (lsec == 0) ? 0 : (lsec == 1) ? 32 : (lsec == 2) ? 96 : 224;
    int slot = (lsec >= 2) ? 4 : ((lsec == 1) ? 2 : 1);
    int off = sec + slot * kk + l;
#pragma unroll
    for (int et = 0; et < NET; ++et)
#pragma unroll
      for (int r = 0; r < 4; ++r)
        rad2[(size_t)rowp[et][r] * 352 + off] = f2bu(acc[et][ct][r]);
  }
}

template <int l>
DEV void unc_one(int a, int k,
                 const float* __restrict__ f0, const float* __restrict__ f1,
                 const float* __restrict__ f2, const float* __restrict__ f3,
                 const float* __restrict__ U, unsigned* __restrict__ dst) {
  constexpr int T2 = (cPL[l] + 1) * (cPL[l] + 1);
  constexpr int M = (l + 1) * (l + 1);
  constexpr int NB = (T2 + 1) / 2;
  constexpr int base = (l == 0) ? 0 : (l == 1) ? 32 : (l == 2) ? 192 : 352;
  const float* fps[4] = {f0, f1, f2, f3};
  float fc[M];
#pragma unroll
  for (int lp = 0; lp <= l; ++lp) {
    const float* fp = fps[lp];
#pragma unroll
    for (int mm = 0; mm < 2 * lp + 1; ++mm)
      fc[lp * lp + mm] = fp[((long)a * (2 * lp + 1) + mm) * cK[lp] + cLO[l] + k];
  }
  float v[T2];
#pragma unroll
  for (int q = 0; q < T2; ++q) {
    float s = 0.f;
#pragma unroll
    for (int m = 0; m < M; ++m) s += U[q * T2 + m] * fc[m];
    v[q] = s;
  }
#pragma unroll
  for (int q2 = 0; q2 < NB; ++q2) {
    float a0 = v[2 * q2];
    float a1 = (2 * q2 + 1 < T2) ? v[2 * q2 + 1] : 0.f;
    dst[base + q2 * 32 + k] = pk2(a0, a1);
  }
}

// sph(5000) | radial(2500) | uncfeat(313)
__global__ __launch_bounds__(256) void k_mid(
    const float* __restrict__ rb0, const float* __restrict__ rb1,
    const float* __restrict__ rb2, const float* __restrict__ rb3,
    const float* __restrict__ s0p, const float* __restrict__ s1p,
    const float* __restrict__ s2p, const float* __restrict__ s3p,
    const float* __restrict__ f0, const float* __restrict__ f1,
    const float* __restrict__ f2, const float* __restrict__ f3,
    const float* __restrict__ w10, const float* __restrict__ w11,
    const float* __restrict__ w12, const float* __restrict__ w13,
    const float* __restrict__ w20, const float* __restrict__ w21,
    const float* __restrict__ w22, const float* __restrict__ w23,
    const float* __restrict__ u0, const float* __restrict__ u2,
    const float* __restrict__ u4, const int* __restrict__ inv,
    unsigned short* __restrict__ rad2, unsigned short* __restrict__ S2v,
    unsigned* __restrict__ unc3) {
  __shared__ __align__(16) unsigned short H[64][72];
  __shared__ float UL[707];
  int b = blockIdx.x;
  int tid = threadIdx.x;
  if (b < 5000) {
    for (int idx = tid; idx < 707; idx += 256)
      UL[idx] = (idx == 0) ? u0[0] : (idx < 82 ? u2[idx - 1] : u4[idx - 82]);
    __syncthreads();
    int e = b * 8 + (tid >> 5);
    sph_body(e, tid & 31, s0p, s1p, s2p, s3p, UL, inv, S2v);
  } else if (b < 7500) {
    int rbk = b - 5000;
    int l = rbk / 625;
    int e0 = (rbk - l * 625) * 64;
    switch (l) {
      case 0: radial_body<0>(rb0, w10, w20, inv, rad2, e0, tid, H); break;
      case 1: radial_body<1>(rb1, w11, w21, inv, rad2, e0, tid, H); break;
      case 2: radial_body<2>(rb2, w12, w22, inv, rad2, e0, tid, H); break;
      default: radial_body<3>(rb3, w13, w23, inv, rad2, e0, tid, H); break;
    }
  } else {
    for (int idx = tid; idx < 707; idx += 256)
      UL[idx] = (idx == 0) ? u0[0] : (idx < 82 ? u2[idx - 1] : u4[idx - 82]);
    __syncthreads();
    int a = (b - 7500) * 8 + (tid >> 5);
    if (a >= N_ATOMS) return;
    int k = tid & 31;
    unsigned* dst = unc3 + (size_t)a * 768;
    unc_one<0>(a, k, f0, f1, f2, f3, UL, dst);
    unc_one<1>(a, k, f0, f1, f2, f3, UL + 1, dst);
    unc_one<2>(a, k, f0, f1, f2, f3, UL + 1, dst);
    unc_one<3>(a, k, f0, f1, f2, f3, UL + 82, dst);
  }
}

// ---------------- k_edge8: l-split role waves, register-only epilogue ----------------
template <int C, int SHIFT>
DEV void couple_one(const float* __restrict__ Ush, const float* __restrict__ acc,
                    unsigned short* __restrict__ crow, int kk) {
  constexpr int l  = ccl[C];
  constexpr int mm = ccm[C];
  constexpr int lp = l + ccs[C];
  constexpr int T  = cPL[lp] + 1;
  constexpr int T2 = T * T;
  constexpr int m  = l * l + mm;
  constexpr int ub = (lp == 0) ? 0 : (lp == 3 ? 82 : 1);
  float s = 0.f;
#pragma unroll
  for (int q = 0; q < T2; ++q)
    s += Ush[ub + q * T2 + m] * acc[cAOF[lp] - SHIFT + q];
  crow[C * 32 + kk] = f2bu(s);
}

__global__ __launch_bounds__(256) void k_edge8(
    const int* __restrict__ start, const int* __restrict__ nlist,
    const float* __restrict__ u0, const float* __restrict__ u2,
    const float* __restrict__ u4,
    const unsigned short* __restrict__ rad2, const unsigned short* __restrict__ S2v,
    const unsigned* __restrict__ unc3, unsigned short* __restrict__ ccg) {
  __shared__ float Ush[707];
  int tid = threadIdx.x;
  for (int idx = tid; idx < 707; idx += 256)
    Ush[idx] = (idx == 0) ? u0[0] : (idx < 82 ? u2[idx - 1] : u4[idx - 82]);
  __syncthreads();
  int wv = tid >> 6;
  int lane = tid & 63;
  int k = lane & 31;
  int strm = lane >> 5;            // 2 streams per wave
  int a = blockIdx.x * 2 + (wv >> 1);
  int role = wv & 1;               // 0: l0+l1+l2 ; 1: l3
  int beg = start[a], end = start[a + 1];
  unsigned short* crow = ccg + (size_t)a * 960;

  if (role == 0) {
    int q9 = (k < 9) ? k : 8;
    float acc[19];
#pragma unroll
    for (int j = 0; j < 19; ++j) acc[j] = 0.f;
    int i = beg + strm;
    int neC = 0;
    if (i < end) neC = nlist[i];
    while (i < end) {
      int i2 = i + 2;
      int neN = (i2 < end) ? nlist[i2] : 0;
      const unsigned short* rr = rad2 + (size_t)i * 352;
      const unsigned short* sr = S2v + (size_t)i * 168;
      const unsigned* fr = unc3 + (size_t)neC * 768;

      float rv0 = bu2f(rr[k]);
      unsigned u1v = *reinterpret_cast<const unsigned*>(rr + 32 + 2 * k);
      uint2 u2v = *reinterpret_cast<const uint2*>(rr + 96 + 4 * k);
      float s0v = bu2f(sr[0]);
      unsigned su1 = *reinterpret_cast<const unsigned*>(sr + 2 + 2 * q9);
      uint2 su2 = *reinterpret_cast<const uint2*>(sr + 24 + 4 * q9);
      unsigned fd0 = fr[k];
      unsigned fu1[5], fu2[5];
#pragma unroll
      for (int j = 0; j < 5; ++j) fu1[j] = fr[32 + j * 32 + k];
#pragma unroll
      for (int j = 0; j < 5; ++j) fu2[j] = fr[192 + j * 32 + k];

      acc[0] += rv0 * s0v * lo2f(fd0);
      {
        float ra = lo2f(u1v), rb_ = hi2f(u1v);
        float V[9];
#pragma unroll
        for (int q = 0; q < 9; ++q) {
          unsigned s = (unsigned)__shfl((int)su1, q, 32);
          V[q] = ra * lo2f(s) + rb_ * hi2f(s);
        }
#pragma unroll
        for (int i3 = 0; i3 < 3; ++i3)
#pragma unroll
          for (int j3 = 0; j3 < 3; ++j3) {
            float c = 0.f;
#pragma unroll
            for (int t = 0; t < 3; ++t) {
              int idx = t * 3 + j3;
              float F = (idx & 1) ? hi2f(fu1[idx >> 1]) : lo2f(fu1[idx >> 1]);
              c += V[i3 * 3 + t] * F;
            }
            acc[1 + i3 * 3 + j3] += c;
          }
      }
      {
        float ra = lo2f(u2v.x), rb_ = hi2f(u2v.x), rc = lo2f(u2v.y);
        float V[9];
#pragma unroll
        for (int q = 0; q < 9; ++q) {
          unsigned sx = (unsigned)__shfl((int)su2.x, q, 32);
          unsigned sy = (unsigned)__shfl((int)su2.y, q, 32);
          V[q] = ra * lo2f(sx) + rb_ * hi2f(sx) + rc * lo2f(sy);
        }
#pragma unroll
        for (int i3 = 0; i3 < 3; ++i3)
#pragma unroll
          for (int j3 = 0; j3 < 3; ++j3) {
            float c = 0.f;
#pragma unroll
            for (int t = 0; t < 3; ++t) {
              int idx = t * 3 + j3;
              float F = (idx & 1) ? hi2f(fu2[idx >> 1]) : lo2f(fu2[idx >> 1]);
              c += V[i3 * 3 + t] * F;
            }
            acc[10 + i3 * 3 + j3] += c;
          }
      }
      i = i2; neC = neN;
    }
#pragma unroll
    for (int j = 0; j < 19; ++j) acc[j] += __shfl_xor(acc[j], 32);
    if (lane < 32) {
      couple_one<0, 0>(Ush, acc, crow, k);
      couple_one<1, 0>(Ush, acc, crow, k);
      couple_one<2, 0>(Ush, acc, crow, k);
      couple_one<4, 0>(Ush, acc, crow, k);
      couple_one<5, 0>(Ush, acc, crow, k);
      couple_one<7, 0>(Ush, acc, crow, k);
      couple_one<8, 0>(Ush, acc, crow, k);
    } else {
      couple_one<10, 0>(Ush, acc, crow, k);
      couple_one<11, 0>(Ush, acc, crow, k);
      couple_one<13, 0>(Ush, acc, crow, k);
      couple_one<15, 0>(Ush, acc, crow, k);
      couple_one<17, 0>(Ush, acc, crow, k);
      couple_one<19, 0>(Ush, acc, crow, k);
      couple_one<21, 0>(Ush, acc, crow, k);
    }
  } else {
    int q25 = (k < 25) ? k : 24;
    float acc[25];
#pragma unroll
    for (int j = 0; j < 25; ++j) acc[j] = 0.f;
    int i = beg + strm;
    int neC = 0;
    if (i < end) neC = nlist[i];
    while (i < end) {
      int i2 = i + 2;
      int neN = (i2 < end) ? nlist[i2] : 0;
      const unsigned short* rr = rad2 + (size_t)i * 352;
      const unsigned short* sr = S2v + (size_t)i * 168;
      const unsigned* fr = unc3 + (size_t)neC * 768;

      uint2 u3v = *reinterpret_cast<const uint2*>(rr + 224 + 4 * k);
      uint2 su3 = *reinterpret_cast<const uint2*>(sr + 64 + 4 * q25);
      unsigned fu3[13];
#pragma unroll
      for (int j = 0; j < 13; ++j) fu3[j] = fr[352 + j * 32 + k];

      float ra = lo2f(u3v.x), rb_ = hi2f(u3v.x), rc = lo2f(u3v.y), rd = hi2f(u3v.y);
#pragma unroll
      for (int i5 = 0; i5 < 5; ++i5) {
        float V5[5];
#pragma unroll
        for (int t = 0; t < 5; ++t) {
          int q = i5 * 5 + t;
          unsigned sx = (unsigned)__shfl((int)su3.x, q, 32);
          unsigned sy = (unsigned)__shfl((int)su3.y, q, 32);
          V5[t] = ra * lo2f(sx) + rb_ * hi2f(sx) + rc * lo2f(sy) + rd * hi2f(sy);
        }
#pragma unroll
        for (int j5 = 0; j5 < 5; ++j5) {
          float c = 0.f;
#pragma unroll
          for (int t = 0; t < 5; ++t) {
            int idx = t * 5 + j5;
            float F = (idx & 1) ? hi2f(fu3[idx >> 1]) : lo2f(fu3[idx >> 1]);
            c += V5[t] * F;
          }
          acc[i5 * 5 + j5] += c;
        }
      }
      i = i2; neC = neN;
    }
#pragma unroll
    for (int j = 0; j < 25; ++j) acc[j] += __shfl_xor(acc[j], 32);
    if (lane < 32) {
      couple_one<3, 19>(Ush, acc, crow, k);
      couple_one<6, 19>(Ush, acc, crow, k);
      couple_one<9, 19>(Ush, acc, crow, k);
      couple_one<12, 19>(Ush, acc, crow, k);
      couple_one<14, 19>(Ush, acc, crow, k);
      couple_one<16, 19>(Ush, acc, crow, k);
      couple_one<18, 19>(Ush, acc, crow, k);
      couple_one<20, 19>(Ush, acc, crow, k);
    } else {
      couple_one<22, 19>(Ush, acc, crow, k);
      couple_one<23, 19>(Ush, acc, crow, k);
      couple_one<24, 19>(Ush, acc, crow, k);
      couple_one<25, 19>(Ush, acc, crow, k);
      couple_one<26, 19>(Ush, acc, crow, k);
      couple_one<27, 19>(Ush, acc, crow, k);
      couple_one<28, 19>(Ush, acc, crow, k);
      couple_one<29, 19>(Ush, acc, crow, k);
    }
  }
}

// ---------------- k_out2: MFMA GEMM  out = feats + concat @ Wl ----------------
template <int l>
DEV void out_body(const float* __restrict__ ft, const float* __restrict__ wl,
                  const unsigned short* __restrict__ ccg, float* __restrict__ out,
                  int rt, int tid) {
  constexpr int NMM = 2 * l + 1;
  constexpr int K   = cK[l];
  constexpr int NKS = K / 32;
  constexpr int M   = N_ATOMS * NMM;
  constexpr int NET = (l <= 1) ? 4 : (l == 2 ? 2 : 1);
  int wv = tid >> 6, lane = tid & 63;
  int c0, et0;
  bool active = true;
  if constexpr (l == 0)      { c0 = wv * 32;       et0 = 0; }
  else if constexpr (l == 1) { c0 = wv * 32;       et0 = 0; active = (wv < 3); }
  else if constexpr (l == 2) { c0 = (wv & 1) * 32; et0 = (wv >> 1) * 2; }
  else                       { c0 = 0;             et0 = wv; }
  if (!active) return;
  int ln15 = lane & 15, lhi = lane >> 4;
  int r0 = rt * 64;
  short8 Bf[2][NKS];
#pragma unroll
  for (int ct = 0; ct < 2; ++ct)
#pragma unroll
    for (int ks = 0; ks < NKS; ++ks) {
      int col = c0 + ct * 16 + ln15;
      int kb  = ks * 32 + lhi * 8;
#pragma unroll
      for (int i = 0; i < 8; ++i)
        Bf[ct][ks][i] = f2bs(wl[(long)(kb + i) * K + col]);
    }
  long abase[NET];
#pragma unroll
  for (int et = 0; et < NET; ++et) {
    int R = r0 + (et0 + et) * 16 + ln15;
    if (R >= M) R = M - 1;
    int a = R / NMM, mm = R - a * NMM;
    abase[et] = (long)a * 960 + cCB[l] + (long)mm * K;
  }
  f32x4 acc[NET][2];
#pragma unroll
  for (int et = 0; et < NET; ++et)
#pragma unroll
    for (int ct = 0; ct < 2; ++ct) acc[et][ct] = (f32x4){0.f, 0.f, 0.f, 0.f};
#pragma unroll
  for (int et = 0; et < NET; ++et) {
#pragma unroll
    for (int ks = 0; ks < NKS; ++ks) {
      short8 Af = *reinterpret_cast<const short8*>(&ccg[abase[et] + ks * 32 + lhi * 8]);
      acc[et][0] = __builtin_amdgcn_mfma_f32_16x16x32_bf16(Af, Bf[0][ks], acc[et][0], 0, 0, 0);
      acc[et][1] = __builtin_amdgcn_mfma_f32_16x16x32_bf16(Af, Bf[1][ks], acc[et][1], 0, 0, 0);
    }
  }
#pragma unroll
  for (int et = 0; et < NET; ++et)
#pragma unroll
    for (int ct = 0; ct < 2; ++ct)
#pragma unroll
      for (int r = 0; r < 4; ++r) {
        int R = r0 + (et0 + et) * 16 + lhi * 4 + r;
        if (R < M) {
          int col = c0 + ct * 16 + ln15;
          long o = (long)R * K + col;
          out[cOUT[l] + o] = ft[o] + acc[et][ct][r];
        }
      }
}

__global__ __launch_bounds__(256) void k_out2(
    const float* __restrict__ f0, const float* __restrict__ f1,
    const float* __restrict__ f2, const float* __restrict__ f3,
    const float* __restrict__ wl0, const float* __restrict__ wl1,
    const float* __restrict__ wl2, const float* __restrict__ wl3,
    const unsigned short* __restrict__ ccg, float* __restrict__ out) {
  int b = blockIdx.x;
  int tid = threadIdx.x;
  if      (b < 40)  out_body<0>(f0, wl0, ccg, out, b,       tid);
  else if (b < 158) out_body<1>(f1, wl1, ccg, out, b - 40,  tid);
  else if (b < 354) out_body<2>(f2, wl2, ccg, out, b - 158, tid);
  else              out_body<3>(f3, wl3, ccg, out, b - 354, tid);
}

// ---------------- launch ----------------
extern "C" void kernel_launch(void* const* d_in, const int* in_sizes, int n_in,
                              void* d_out, int out_size, void* d_ws, size_t ws_size,
                              hipStream_t stream) {
  (void)n_in; (void)out_size; (void)ws_size;
  bool dictord = (in_sizes[1] == 40000);
  const float* rb[4]; const float* sph[4]; const float* ft[4];
  const float *w1[4], *w2[4], *wl[4];
  for (int l = 0; l < 4; ++l) {
    if (dictord) {
      rb[l]  = (const float*)d_in[3 * l + 0];
      sph[l] = (const float*)d_in[3 * l + 1];
      ft[l]  = (const float*)d_in[3 * l + 2];
      w1[l]  = (const float*)d_in[17 + 3 * l];
      w2[l]  = (const float*)d_in[18 + 3 * l];
      wl[l]  = (const float*)d_in[19 + 3 * l];
    } else {
      rb[l]  = (const float*)d_in[l];
      sph[l] = (const float*)d_in[4 + l];
      ft[l]  = (const float*)d_in[8 + l];
      w1[l]  = (const float*)d_in[17 + l];
      w2[l]  = (const float*)d_in[21 + l];
      wl[l]  = (const float*)d_in[25 + l];
    }
  }
  const int* centers   = (const int*)d_in[12];
  const int* neighbors = (const int*)d_in[13];
  const float* u0 = (const float*)d_in[14];
  const float* u2 = (const float*)d_in[15];
  const float* u4 = (const float*)d_in[16];

  float* ws = (float*)d_ws;
  unsigned short* rad2 = (unsigned short*)(ws + RAD2_OFF);
  unsigned short* S2v  = (unsigned short*)(ws + S2_OFF);
  unsigned*       unc3 = (unsigned*)(ws + UNC3_OFF);
  unsigned short* ccg  = (unsigned short*)(ws + CCG_OFF);
  int* cnt   = (int*)(ws + CNT_OFF);
  int* start = (int*)(ws + START_OFF);
  int* fill  = (int*)(ws + FILL_OFF);
  int* inv   = (int*)(ws + INV_OFF);
  int* nlist = (int*)(ws + NLIST_OFF);

  hipMemsetAsync(cnt, 0, N_ATOMS * sizeof(int), stream);
  k_count<<<157, 256, 0, stream>>>(centers, cnt);
  k_scan<<<1, 256, 0, stream>>>(cnt, start, fill);
  k_fill<<<157, 256, 0, stream>>>(centers, neighbors, fill, inv, nlist);
  k_mid<<<7813, 256, 0, stream>>>(rb[0], rb[1], rb[2], rb[3],
                                  sph[0], sph[1], sph[2], sph[3],
                                  ft[0], ft[1], ft[2], ft[3],
                                  w1[0], w1[1], w1[2], w1[3],
                                  w2[0], w2[1], w2[2], w2[3],
                                  u0, u2, u4, inv, rad2, S2v, unc3);
  k_edge8<<<1250, 256, 0, stream>>>(start, nlist, u0, u2, u4,
                                    rad2, S2v, unc3, ccg);
  k_out2<<<628, 256, 0, stream>>>(ft[0], ft[1], ft[2], ft[3],
                                  wl[0], wl[1], wl[2], wl[3], ccg, (float*)d_out);
}

// Round 16
// 116.274 us; speedup vs baseline: 1.0891x; 1.0891x over previous
//
#include <hip/hip_runtime.h>
#include <hip/hip_bf16.h>

typedef __hip_bfloat16 bf16;
using short8 = __attribute__((ext_vector_type(8))) short;
using f32x4  = __attribute__((ext_vector_type(4))) float;

#define DEV static __device__ __forceinline__

DEV unsigned short f2bu(float f) {
  union { bf16 h; unsigned short u; } v; v.h = __float2bfloat16(f); return v.u;
}
DEV short f2bs(float f) {
  union { bf16 h; short s; } v; v.h = __float2bfloat16(f); return v.s;
}
DEV float bu2f(unsigned short u) {
  union { unsigned x; float f; } v; v.x = ((unsigned)u) << 16; return v.f;
}
DEV float lo2f(unsigned u) { union { unsigned x; float f; } v; v.x = u << 16; return v.f; }
DEV float hi2f(unsigned u) { union { unsigned x; float f; } v; v.x = u & 0xFFFF0000u; return v.f; }
DEV unsigned pk2(float a, float b) { return (unsigned)f2bu(a) | ((unsigned)f2bu(b) << 16); }

// ---- problem constants ----
#define N_ATOMS 2500
#define N_EDGES 40000

constexpr int cK[4]    = {128, 96, 64, 32};
constexpr int cPL[4]   = {0, 2, 2, 4};
constexpr int cLO[4]   = {96, 64, 32, 0};
constexpr int cAOF[4]  = {0, 1, 10, 19};
// ws float-offsets
constexpr int RAD2_OFF = 53248;                        // [pos][352 ushorts]
constexpr int SPHP_OFF = RAD2_OFF + N_EDGES * 176;     // [pos][16 floats]
constexpr int UNC3_OFF = SPHP_OFF + N_EDGES * 84;      // [a][768 dwords] (offset kept from prior layout)
constexpr int CCG_OFF  = UNC3_OFF + N_ATOMS * 768;     // [a][960 bf16]
constexpr int CSR_OFF   = CCG_OFF + N_ATOMS * 480;
constexpr int CNT_OFF   = CSR_OFF;
constexpr int START_OFF = CSR_OFF + 2500;
constexpr int FILL_OFF  = CSR_OFF + 5008;
constexpr int ELIST_OFF = CSR_OFF + 7512;              // [pos] -> edge id
constexpr int NLIST_OFF = CSR_OFF + 87512;             // [pos] -> neighbor atom

constexpr int cCB[4]  = {0, 128, 416, 736};
constexpr int cOUT[4] = {0, 320000, 1040000, 1840000};

// couple/concat combo tables (constexpr for compile-time folding)
constexpr int ccl[30] = {0,0,0,0, 1,1,1,1,1,1,1,1,1, 2,2,2,2,2,2,2,2,2,2, 3,3,3,3,3,3,3};
constexpr int ccm[30] = {0,0,0,0, 0,0,0,1,1,1,2,2,2, 0,0,1,1,2,2,3,3,4,4, 0,1,2,3,4,5,6};
constexpr int ccs[30] = {0,1,2,3, 0,1,2,0,1,2,0,1,2, 0,1,0,1,0,1,0,1,0,1, 0,0,0,0,0,0,0};

// ---------------- k_count ----------------
__global__ __launch_bounds__(256) void k_count(const int* __restrict__ centers, int* __restrict__ cnt) {
  int e = blockIdx.x * 256 + threadIdx.x;
  if (e < N_EDGES) atomicAdd(&cnt[centers[e]], 1);
}

// ---------------- k_scan ----------------
__global__ __launch_bounds__(256) void k_scan(const int* __restrict__ cnt,
                                              int* __restrict__ start, int* __restrict__ fill) {
  __shared__ int part[256];
  int t = threadIdx.x;
  int loc[10];
  int s = 0;
  int base = t * 10;
#pragma unroll
  for (int i = 0; i < 10; ++i) {
    int c = (base + i < N_ATOMS) ? cnt[base + i] : 0;
    loc[i] = s; s += c;
  }
  part[t] = s;
  __syncthreads();
  for (int off = 1; off < 256; off <<= 1) {
    int v = part[t];
    if (t >= off) v += part[t - off];
    __syncthreads();
    part[t] = v;
    __syncthreads();
  }
  int excl = (t == 0) ? 0 : part[t - 1];
#pragma unroll
  for (int i = 0; i < 10; ++i) {
    if (base + i < N_ATOMS) {
      start[base + i] = excl + loc[i];
      fill[base + i]  = excl + loc[i];
    }
  }
  if (t == 255) start[N_ATOMS] = part[255];
}

// ---------------- k_fill: elist/nlist + packed sph values (elist order) ----------------
__global__ __launch_bounds__(256) void k_fill(const int* __restrict__ centers,
                                              const int* __restrict__ neighbors,
                                              const float* __restrict__ s0p, const float* __restrict__ s1p,
                                              const float* __restrict__ s2p, const float* __restrict__ s3p,
                                              int* __restrict__ fill, int* __restrict__ elist,
                                              int* __restrict__ nlist, float* __restrict__ sphp) {
  int e = blockIdx.x * 256 + threadIdx.x;
  if (e >= N_EDGES) return;
  int pos = atomicAdd(&fill[centers[e]], 1);
  elist[pos] = e;
  nlist[pos] = neighbors[e];
  float* sp = sphp + (size_t)pos * 16;
  sp[0] = s0p[e];
#pragma unroll
  for (int m = 0; m < 3; ++m) sp[1 + m] = s1p[(long)e * 3 + m];
#pragma unroll
  for (int m = 0; m < 5; ++m) sp[4 + m] = s2p[(long)e * 5 + m];
#pragma unroll
  for (int m = 0; m < 7; ++m) sp[9 + m] = s3p[(long)e * 7 + m];
}

// ---------------- k_mid pieces ----------------
template <int l>
DEV void radial_body(const float* __restrict__ rb, const float* __restrict__ Wr1f,
                     const float* __restrict__ w2, const int* __restrict__ elist,
                     unsigned short* __restrict__ rad2,
                     int p0, int tid, unsigned short (*H)[72]) {
  constexpr int NM = (l == 0) ? 8 : (l == 1) ? 6 : (l == 2) ? 4 : 2;
  constexpr int K  = cK[l];
  {
    int e  = elist[p0 + (tid & 63)];
    int j0 = (tid >> 6) * 16;
    float rbv[NM];
#pragma unroll
    for (int n = 0; n < NM; ++n) rbv[n] = rb[(long)e * NM + n];
    float h[16];
#pragma unroll
    for (int j = 0; j < 16; ++j) h[j] = 0.f;
#pragma unroll
    for (int n = 0; n < NM; ++n) {
      float rv = rbv[n];
      const float4* wp = reinterpret_cast<const float4*>(Wr1f + n * 64 + j0);
#pragma unroll
      for (int qq = 0; qq < 4; ++qq) {
        float4 w = wp[qq];
        h[4 * qq + 0] += rv * w.x;
        h[4 * qq + 1] += rv * w.y;
        h[4 * qq + 2] += rv * w.z;
        h[4 * qq + 3] += rv * w.w;
      }
    }
    unsigned short* hrow = H[tid & 63];
#pragma unroll
    for (int j = 0; j < 16; j += 2) {
      float a0 = h[j], a1 = h[j + 1];
      a0 = a0 * (1.0f / (1.0f + __expf(-a0)));
      a1 = a1 * (1.0f / (1.0f + __expf(-a1)));
      *reinterpret_cast<unsigned*>(&hrow[j0 + j]) = pk2(a0, a1);
    }
  }
  __syncthreads();
  int wv = tid >> 6, lane = tid & 63;
  constexpr int NET = (l <= 1) ? 4 : (l == 2 ? 2 : 1);
  int c0, et0;
  bool active = true;
  if constexpr (l == 0)      { c0 = wv * 32;       et0 = 0; }
  else if constexpr (l == 1) { c0 = wv * 32;       et0 = 0; active = (wv < 3); }
  else if constexpr (l == 2) { c0 = (wv & 1) * 32; et0 = (wv >> 1) * 2; }
  else                       { c0 = 0;             et0 = wv; }
  if (!active) return;
  int ln15 = lane & 15, lhi = lane >> 4;
  short8 Bf[2][2];
#pragma unroll
  for (int ct = 0; ct < 2; ++ct)
#pragma unroll
    for (int ks = 0; ks < 2; ++ks) {
      int col = c0 + ct * 16 + ln15;
      int kb  = ks * 32 + lhi * 8;
#pragma unroll
      for (int i = 0; i < 8; ++i)
        Bf[ct][ks][i] = f2bs(w2[(long)(kb + i) * K + col]);
    }
  f32x4 acc[NET][2];
#pragma unroll
  for (int et = 0; et < NET; ++et)
#pragma unroll
    for (int ct = 0; ct < 2; ++ct) acc[et][ct] = (f32x4){0.f, 0.f, 0.f, 0.f};
#pragma unroll
  for (int et = 0; et < NET; ++et) {
#pragma unroll
    for (int ks = 0; ks < 2; ++ks) {
      short8 Af = *reinterpret_cast<const short8*>(&H[(et0 + et) * 16 + ln15][ks * 32 + lhi * 8]);
      acc[et][0] = __builtin_amdgcn_mfma_f32_16x16x32_bf16(Af, Bf[0][ks], acc[et][0], 0, 0, 0);
      acc[et][1] = __builtin_amdgcn_mfma_f32_16x16x32_bf16(Af, Bf[1][ks], acc[et][1], 0, 0, 0);
    }
  }
#pragma unroll
  for (int ct = 0; ct < 2; ++ct) {
    int c = c0 + ct * 16 + ln15;
    int lsec = 3 - (c >> 5);
    int kk = c & 31;
    int sec  = (lsec == 0) ? 0 : (lsec == 1) ? 32 : (lsec == 2) ? 96 : 224;
    int slot = (lsec >= 2) ? 4 : ((lsec == 1) ? 2 : 1);
    int off = sec + slot * kk + l;
#pragma unroll
    for (int et = 0; et < NET; ++et)
#pragma unroll
      for (int r = 0; r < 4; ++r) {
        int row = p0 + (et0 + et) * 16 + lhi * 4 + r;
        rad2[(size_t)row * 352 + off] = f2bu(acc[et][ct][r]);
      }
  }
}

template <int l>
DEV void unc_one(int a, int k,
                 const float* __restrict__ f0, const float* __restrict__ f1,
                 const float* __restrict__ f2, const float* __restrict__ f3,
                 const float* __restrict__ U, unsigned* __restrict__ dst) {
  constexpr int T2 = (cPL[l] + 1) * (cPL[l] + 1);
  constexpr int M = (l + 1) * (l + 1);
  constexpr int NB = (T2 + 1) / 2;
  constexpr int base = (l == 0) ? 0 : (l == 1) ? 32 : (l == 2) ? 192 : 352;
  const float* fps[4] = {f0, f1, f2, f3};
  float fc[M];
#pragma unroll
  for (int lp = 0; lp <= l; ++lp) {
    const float* fp = fps[lp];
#pragma unroll
    for (int mm = 0; mm < 2 * lp + 1; ++mm)
      fc[lp * lp + mm] = fp[((long)a * (2 * lp + 1) + mm) * cK[lp] + cLO[l] + k];
  }
  float v[T2];
#pragma unroll
  for (int q = 0; q < T2; ++q) {
    float s = 0.f;
#pragma unroll
    for (int m = 0; m < M; ++m) s += U[q * T2 + m] * fc[m];
    v[q] = s;
  }
#pragma unroll
  for (int q2 = 0; q2 < NB; ++q2) {
    float a0 = v[2 * q2];
    float a1 = (2 * q2 + 1 < T2) ? v[2 * q2 + 1] : 0.f;
    dst[base + q2 * 32 + k] = pk2(a0, a1);
  }
}

// radial(2500) | uncfeat(313)
__global__ __launch_bounds__(256) void k_mid(
    const float* __restrict__ rb0, const float* __restrict__ rb1,
    const float* __restrict__ rb2, const float* __restrict__ rb3,
    const float* __restrict__ f0, const float* __restrict__ f1,
    const float* __restrict__ f2, const float* __restrict__ f3,
    const float* __restrict__ w10, const float* __restrict__ w11,
    const float* __restrict__ w12, const float* __restrict__ w13,
    const float* __restrict__ w20, const float* __restrict__ w21,
    const float* __restrict__ w22, const float* __restrict__ w23,
    const float* __restrict__ u0, const float* __restrict__ u2,
    const float* __restrict__ u4, const int* __restrict__ elist,
    unsigned short* __restrict__ rad2, unsigned* __restrict__ unc3) {
  __shared__ __align__(16) unsigned short H[64][72];
  __shared__ float UL[707];
  int b = blockIdx.x;
  int tid = threadIdx.x;
  if (b < 2500) {
    int l = b / 625;
    int p0 = (b - l * 625) * 64;
    switch (l) {
      case 0: radial_body<0>(rb0, w10, w20, elist, rad2, p0, tid, H); break;
      case 1: radial_body<1>(rb1, w11, w21, elist, rad2, p0, tid, H); break;
      case 2: radial_body<2>(rb2, w12, w22, elist, rad2, p0, tid, H); break;
      default: radial_body<3>(rb3, w13, w23, elist, rad2, p0, tid, H); break;
    }
  } else {
    for (int idx = tid; idx < 707; idx += 256)
      UL[idx] = (idx == 0) ? u0[0] : (idx < 82 ? u2[idx - 1] : u4[idx - 82]);
    __syncthreads();
    int a = (b - 2500) * 8 + (tid >> 5);
    if (a >= N_ATOMS) return;
    int k = tid & 31;
    unsigned* dst = unc3 + (size_t)a * 768;
    unc_one<0>(a, k, f0, f1, f2, f3, UL, dst);
    unc_one<1>(a, k, f0, f1, f2, f3, UL + 1, dst);
    unc_one<2>(a, k, f0, f1, f2, f3, UL + 1, dst);
    unc_one<3>(a, k, f0, f1, f2, f3, UL + 82, dst);
  }
}

// ---------------- k_edge9: l-split role waves, inline S, register-only epilogue ----------------
template <int C, int SHIFT>
DEV void couple_one(const float* __restrict__ Ush, const float* __restrict__ acc,
                    unsigned short* __restrict__ crow, int kk) {
  constexpr int l  = ccl[C];
  constexpr int mm = ccm[C];
  constexpr int lp = l + ccs[C];
  constexpr int T  = cPL[lp] + 1;
  constexpr int T2 = T * T;
  constexpr int m  = l * l + mm;
  constexpr int ub = (lp == 0) ? 0 : (lp == 3 ? 82 : 1);
  float s = 0.f;
#pragma unroll
  for (int q = 0; q < T2; ++q)
    s += Ush[ub + q * T2 + m] * acc[cAOF[lp] - SHIFT + q];
  crow[C * 32 + kk] = f2bu(s);
}

__global__ __launch_bounds__(256) void k_edge9(
    const int* __restrict__ start, const int* __restrict__ nlist,
    const float* __restrict__ u0, const float* __restrict__ u2,
    const float* __restrict__ u4, const float* __restrict__ sphp,
    const unsigned short* __restrict__ rad2,
    const unsigned* __restrict__ unc3, unsigned short* __restrict__ ccg) {
  __shared__ float Ush[707];
  int tid = threadIdx.x;
  for (int idx = tid; idx < 707; idx += 256)
    Ush[idx] = (idx == 0) ? u0[0] : (idx < 82 ? u2[idx - 1] : u4[idx - 82]);
  __syncthreads();
  int wv = tid >> 6;
  int lane = tid & 63;
  int k = lane & 31;
  int strm = lane >> 5;            // 2 streams per wave
  int a = blockIdx.x * 2 + (wv >> 1);
  int role = wv & 1;               // 0: l0+l1+l2 ; 1: l3
  int beg = start[a], end = start[a + 1];
  unsigned short* crow = ccg + (size_t)a * 960;

  if (role == 0) {
    int q9 = (k < 9) ? k : 8;
    float u0v = Ush[0];
    float u2r[9];
#pragma unroll
    for (int j = 0; j < 9; ++j) u2r[j] = Ush[1 + q9 * 9 + j];
    float acc[19];
#pragma unroll
    for (int j = 0; j < 19; ++j) acc[j] = 0.f;
    int i = beg + strm;
    int neC = 0;
    if (i < end) neC = nlist[i];
    while (i < end) {
      int i2 = i + 2;
      int neN = (i2 < end) ? nlist[i2] : 0;
      const unsigned short* rr = rad2 + (size_t)i * 352;
      const float* sp = sphp + (size_t)i * 16;
      const unsigned* fr = unc3 + (size_t)neC * 768;

      float rv0 = bu2f(rr[k]);
      unsigned u1v = *reinterpret_cast<const unsigned*>(rr + 32 + 2 * k);
      uint2 u2v = *reinterpret_cast<const uint2*>(rr + 96 + 4 * k);
      float4 A = *reinterpret_cast<const float4*>(sp);
      float4 B = *reinterpret_cast<const float4*>(sp + 4);
      float sp2e = sp[8];
      unsigned fd0 = fr[k];
      unsigned fu1[5], fu2[5];
#pragma unroll
      for (int j = 0; j < 5; ++j) fu1[j] = fr[32 + j * 32 + k];
#pragma unroll
      for (int j = 0; j < 5; ++j) fu2[j] = fr[192 + j * 32 + k];

      // inline S (lane q = q9)
      float s0 = u2r[0] * A.x;
      float s1 = u2r[1] * A.y + u2r[2] * A.z + u2r[3] * A.w;
      float s2 = u2r[4] * B.x + u2r[5] * B.y + u2r[6] * B.z + u2r[7] * B.w + u2r[8] * sp2e;
      unsigned su1 = pk2(s0, s1);
      unsigned su2y = pk2(s2, 0.f);
      float s0v = f2bu(u0v * A.x) ? 0.f : 0.f; // placeholder removed below
      s0v = bu2f(f2bu(u0v * A.x));

      acc[0] += rv0 * s0v * lo2f(fd0);
      {
        float ra = lo2f(u1v), rb_ = hi2f(u1v);
        float V[9];
#pragma unroll
        for (int q = 0; q < 9; ++q) {
          unsigned s = (unsigned)__shfl((int)su1, q, 32);
          V[q] = ra * lo2f(s) + rb_ * hi2f(s);
        }
#pragma unroll
        for (int i3 = 0; i3 < 3; ++i3)
#pragma unroll
          for (int j3 = 0; j3 < 3; ++j3) {
            float c = 0.f;
#pragma unroll
            for (int t = 0; t < 3; ++t) {
              int idx = t * 3 + j3;
              float F = (idx & 1) ? hi2f(fu1[idx >> 1]) : lo2f(fu1[idx >> 1]);
              c += V[i3 * 3 + t] * F;
            }
            acc[1 + i3 * 3 + j3] += c;
          }
      }
      {
        float ra = lo2f(u2v.x), rb_ = hi2f(u2v.x), rc = lo2f(u2v.y);
        float V[9];
#pragma unroll
        for (int q = 0; q < 9; ++q) {
          unsigned sx = (unsigned)__shfl((int)su1, q, 32);
          unsigned sy = (unsigned)__shfl((int)su2y, q, 32);
          V[q] = ra * lo2f(sx) + rb_ * hi2f(sx) + rc * lo2f(sy);
        }
#pragma unroll
        for (int i3 = 0; i3 < 3; ++i3)
#pragma unroll
          for (int j3 = 0; j3 < 3; ++j3) {
            float c = 0.f;
#pragma unroll
            for (int t = 0; t < 3; ++t) {
              int idx = t * 3 + j3;
              float F = (idx & 1) ? hi2f(fu2[idx >> 1]) : lo2f(fu2[idx >> 1]);
              c += V[i3 * 3 + t] * F;
            }
            acc[10 + i3 * 3 + j3] += c;
          }
      }
      i = i2; neC = neN;
    }
#pragma unroll
    for (int j = 0; j < 19; ++j) acc[j] += __shfl_xor(acc[j], 32);
    if (lane < 32) {
      couple_one<0, 0>(Ush, acc, crow, k);
      couple_one<1, 0>(Ush, acc, crow, k);
      couple_one<2, 0>(Ush, acc, crow, k);
      couple_one<4, 0>(Ush, acc, crow, k);
      couple_one<5, 0>(Ush, acc, crow, k);
      couple_one<7, 0>(Ush, acc, crow, k);
      couple_one<8, 0>(Ush, acc, crow, k);
    } else {
      couple_one<10, 0>(Ush, acc, crow, k);
      couple_one<11, 0>(Ush, acc, crow, k);
      couple_one<13, 0>(Ush, acc, crow, k);
      couple_one<15, 0>(Ush, acc, crow, k);
      couple_one<17, 0>(Ush, acc, crow, k);
      couple_one<19, 0>(Ush, acc, crow, k);
      couple_one<21, 0>(Ush, acc, crow, k);
    }
  } else {
    int q25 = (k < 25) ? k : 24;
    float u4r[16];
#pragma unroll
    for (int j = 0; j < 16; ++j) u4r[j] = Ush[82 + q25 * 25 + j];
    float acc[25];
#pragma unroll
    for (int j = 0; j < 25; ++j) acc[j] = 0.f;
    int i = beg + strm;
    int neC = 0;
    if (i < end) neC = nlist[i];
    while (i < end) {
      int i2 = i + 2;
      int neN = (i2 < end) ? nlist[i2] : 0;
      const unsigned short* rr = rad2 + (size_t)i * 352;
      const float* sp = sphp + (size_t)i * 16;
      const unsigned* fr = unc3 + (size_t)neC * 768;

      uint2 u3v = *reinterpret_cast<const uint2*>(rr + 224 + 4 * k);
      float4 A = *reinterpret_cast<const float4*>(sp);
      float4 B = *reinterpret_cast<const float4*>(sp + 4);
      float4 Cc = *reinterpret_cast<const float4*>(sp + 8);
      float4 D = *reinterpret_cast<const float4*>(sp + 12);
      unsigned fu3[13];
#pragma unroll
      for (int j = 0; j < 13; ++j) fu3[j] = fr[352 + j * 32 + k];

      // inline S (lane q = q25)
      float w0 = u4r[0] * A.x;
      float w1 = u4r[1] * A.y + u4r[2] * A.z + u4r[3] * A.w;
      float w2 = u4r[4] * B.x + u4r[5] * B.y + u4r[6] * B.z + u4r[7] * B.w + u4r[8] * Cc.x;
      float w3 = u4r[9] * Cc.y + u4r[10] * Cc.z + u4r[11] * Cc.w
               + u4r[12] * D.x + u4r[13] * D.y + u4r[14] * D.z + u4r[15] * D.w;
      unsigned su3x = pk2(w0, w1), su3y = pk2(w2, w3);

      float ra = lo2f(u3v.x), rb_ = hi2f(u3v.x), rc = lo2f(u3v.y), rd = hi2f(u3v.y);
#pragma unroll
      for (int i5 = 0; i5 < 5; ++i5) {
        float V5[5];
#pragma unroll
        for (int t = 0; t < 5; ++t) {
          int q = i5 * 5 + t;
          unsigned sx = (unsigned)__shfl((int)su3x, q, 32);
          unsigned sy = (unsigned)__shfl((int)su3y, q, 32);
          V5[t] = ra * lo2f(sx) + rb_ * hi2f(sx) + rc * lo2f(sy) + rd * hi2f(sy);
        }
#pragma unroll
        for (int j5 = 0; j5 < 5; ++j5) {
          float c = 0.f;
#pragma unroll
          for (int t = 0; t < 5; ++t) {
            int idx = t * 5 + j5;
            float F = (idx & 1) ? hi2f(fu3[idx >> 1]) : lo2f(fu3[idx >> 1]);
            c += V5[t] * F;
          }
          acc[i5 * 5 + j5] += c;
        }
      }
      i = i2; neC = neN;
    }
#pragma unroll
    for (int j = 0; j < 25; ++j) acc[j] += __shfl_xor(acc[j], 32);
    if (lane < 32) {
      couple_one<3, 19>(Ush, acc, crow, k);
      couple_one<6, 19>(Ush, acc, crow, k);
      couple_one<9, 19>(Ush, acc, crow, k);
      couple_one<12, 19>(Ush, acc, crow, k);
      couple_one<14, 19>(Ush, acc, crow, k);
      couple_one<16, 19>(Ush, acc, crow, k);
      couple_one<18, 19>(Ush, acc, crow, k);
      couple_one<20, 19>(Ush, acc, crow, k);
    } else {
      couple_one<22, 19>(Ush, acc, crow, k);
      couple_one<23, 19>(Ush, acc, crow, k);
      couple_one<24, 19>(Ush, acc, crow, k);
      couple_one<25, 19>(Ush, acc, crow, k);
      couple_one<26, 19>(Ush, acc, crow, k);
      couple_one<27, 19>(Ush, acc, crow, k);
      couple_one<28, 19>(Ush, acc, crow, k);
      couple_one<29, 19>(Ush, acc, crow, k);
    }
  }
}

// ---------------- k_out2: MFMA GEMM  out = feats + concat @ Wl ----------------
template <int l>
DEV void out_body(const float* __restrict__ ft, const float* __restrict__ wl,
                  const unsigned short* __restrict__ ccg, float* __restrict__ out,
                  int rt, int tid) {
  constexpr int NMM = 2 * l + 1;
  constexpr int K   = cK[l];
  constexpr int NKS = K / 32;
  constexpr int M   = N_ATOMS * NMM;
  constexpr int NET = (l <= 1) ? 4 : (l == 2 ? 2 : 1);
  int wv = tid >> 6, lane = tid & 63;
  int c0, et0;
  bool active = true;
  if constexpr (l == 0)      { c0 = wv * 32;       et0 = 0; }
  else if constexpr (l == 1) { c0 = wv * 32;       et0 = 0; active = (wv < 3); }
  else if constexpr (l == 2) { c0 = (wv & 1) * 32; et0 = (wv >> 1) * 2; }
  else                       { c0 = 0;             et0 = wv; }
  if (!active) return;
  int ln15 = lane & 15, lhi = lane >> 4;
  int r0 = rt * 64;
  short8 Bf[2][NKS];
#pragma unroll
  for (int ct = 0; ct < 2; ++ct)
#pragma unroll
    for (int ks = 0; ks < NKS; ++ks) {
      int col = c0 + ct * 16 + ln15;
      int kb  = ks * 32 + lhi * 8;
#pragma unroll
      for (int i = 0; i < 8; ++i)
        Bf[ct][ks][i] = f2bs(wl[(long)(kb + i) * K + col]);
    }
  long abase[NET];
#pragma unroll
  for (int et = 0; et < NET; ++et) {
    int R = r0 + (et0 + et) * 16 + ln15;
    if (R >= M) R = M - 1;
    int a = R / NMM, mm = R - a * NMM;
    abase[et] = (long)a * 960 + cCB[l] + (long)mm * K;
  }
  f32x4 acc[NET][2];
#pragma unroll
  for (int et = 0; et < NET; ++et)
#pragma unroll
    for (int ct = 0; ct < 2; ++ct) acc[et][ct] = (f32x4){0.f, 0.f, 0.f, 0.f};
#pragma unroll
  for (int et = 0; et < NET; ++et) {
#pragma unroll
    for (int ks = 0; ks < NKS; ++ks) {
      short8 Af = *reinterpret_cast<const short8*>(&ccg[abase[et] + ks * 32 + lhi * 8]);
      acc[et][0] = __builtin_amdgcn_mfma_f32_16x16x32_bf16(Af, Bf[0][ks], acc[et][0], 0, 0, 0);
      acc[et][1] = __builtin_amdgcn_mfma_f32_16x16x32_bf16(Af, Bf[1][ks], acc[et][1], 0, 0, 0);
    }
  }
#pragma unroll
  for (int et = 0; et < NET; ++et)
#pragma unroll
    for (int ct = 0; ct < 2; ++ct)
#pragma unroll
      for (int r = 0; r < 4; ++r) {
        int R = r0 + (et0 + et) * 16 + lhi * 4 + r;
        if (R < M) {
          int col = c0 + ct * 16 + ln15;
          long o = (long)R * K + col;
          out[cOUT[l] + o] = ft[o] + acc[et][ct][r];
        }
      }
}

__global__ __launch_bounds__(256) void k_out2(
    const float* __restrict__ f0, const float* __restrict__ f1,
    const float* __restrict__ f2, const float* __restrict__ f3,
    const float* __restrict__ wl0, const float* __restrict__ wl1,
    const float* __restrict__ wl2, const float* __restrict__ wl3,
    const unsigned short* __restrict__ ccg, float* __restrict__ out) {
  int b = blockIdx.x;
  int tid = threadIdx.x;
  if      (b < 40)  out_body<0>(f0, wl0, ccg, out, b,       tid);
  else if (b < 158) out_body<1>(f1, wl1, ccg, out, b - 40,  tid);
  else if (b < 354) out_body<2>(f2, wl2, ccg, out, b - 158, tid);
  else              out_body<3>(f3, wl3, ccg, out, b - 354, tid);
}

// ---------------- launch ----------------
extern "C" void kernel_launch(void* const* d_in, const int* in_sizes, int n_in,
                              void* d_out, int out_size, void* d_ws, size_t ws_size,
                              hipStream_t stream) {
  (void)n_in; (void)out_size; (void)ws_size;
  bool dictord = (in_sizes[1] == 40000);
  const float* rb[4]; const float* sph[4]; const float* ft[4];
  const float *w1[4], *w2[4], *wl[4];
  for (int l = 0; l < 4; ++l) {
    if (dictord) {
      rb[l]  = (const float*)d_in[3 * l + 0];
      sph[l] = (const float*)d_in[3 * l + 1];
      ft[l]  = (const float*)d_in[3 * l + 2];
      w1[l]  = (const float*)d_in[17 + 3 * l];
      w2[l]  = (const float*)d_in[18 + 3 * l];
      wl[l]  = (const float*)d_in[19 + 3 * l];
    } else {
      rb[l]  = (const float*)d_in[l];
      sph[l] = (const float*)d_in[4 + l];
      ft[l]  = (const float*)d_in[8 + l];
      w1[l]  = (const float*)d_in[17 + l];
      w2[l]  = (const float*)d_in[21 + l];
      wl[l]  = (const float*)d_in[25 + l];
    }
  }
  const int* centers   = (const int*)d_in[12];
  const int* neighbors = (const int*)d_in[13];
  const float* u0 = (const float*)d_in[14];
  const float* u2 = (const float*)d_in[15];
  const float* u4 = (const float*)d_in[16];

  float* ws = (float*)d_ws;
  unsigned short* rad2 = (unsigned short*)(ws + RAD2_OFF);
  float*          sphp = ws + SPHP_OFF;
  unsigned*       unc3 = (unsigned*)(ws + UNC3_OFF);
  unsigned short* ccg  = (unsigned short*)(ws + CCG_OFF);
  int* cnt   = (int*)(ws + CNT_OFF);
  int* start = (int*)(ws + START_OFF);
  int* fill  = (int*)(ws + FILL_OFF);
  int* elist = (int*)(ws + ELIST_OFF);
  int* nlist = (int*)(ws + NLIST_OFF);

  hipMemsetAsync(cnt, 0, N_ATOMS * sizeof(int), stream);
  k_count<<<157, 256, 0, stream>>>(centers, cnt);
  k_scan<<<1, 256, 0, stream>>>(cnt, start, fill);
  k_fill<<<157, 256, 0, stream>>>(centers, neighbors, sph[0], sph[1], sph[2], sph[3],
                                  fill, elist, nlist, sphp);
  k_mid<<<2813, 256, 0, stream>>>(rb[0], rb[1], rb[2], rb[3],
                                  ft[0], ft[1], ft[2], ft[3],
                                  w1[0], w1[1], w1[2], w1[3],
                                  w2[0], w2[1], w2[2], w2[3],
                                  u0, u2, u4, elist, rad2, unc3);
  k_edge9<<<1250, 256, 0, stream>>>(start, nlist, u0, u2, u4, sphp,
                                    rad2, unc3, ccg);
  k_out2<<<628, 256, 0, stream>>>(ft[0], ft[1], ft[2], ft[3],
                                  wl[0], wl[1], wl[2], wl[3], ccg, (float*)d_out);
}